// Round 23
// baseline (156.562 us; speedup 1.0000x reference)
//
#include <hip/hip_runtime.h>
#include <hip/hip_bf16.h>

#define NN   120000
#define NP   120064   // 1876 * 64, padded rows
#define EPSV 1e-5f
#define NSLICE 16
#define NMOMB 118     // moment blocks (118 * 1024 rows >= NN)

typedef __attribute__((ext_vector_type(8))) short          short8v;   // bf16 MFMA frag
typedef __attribute__((ext_vector_type(8))) unsigned short ushort8v;
typedef __attribute__((ext_vector_type(4))) float          f32x4;

__device__ __forceinline__ float b2f(unsigned short u) {
    union { unsigned int i; float f; } x; x.i = ((unsigned int)u) << 16; return x.f;
}
__device__ __forceinline__ unsigned short f2b(float f) {
    __hip_bfloat16 h = __float2bfloat16(f);   // RTNE; pairs fuse to v_cvt_pk_bf16_f32
    return *reinterpret_cast<unsigned short*>(&h);
}

// ---------------------------------------------------------------------------
// prep: blocks [0,320): w2/w3/w4 -> bf16 fragment-linear (blocks 0..15 also
//       zero the stat2/3/4 region first). blocks [320,438): feat moments.
// ---------------------------------------------------------------------------
__global__ __launch_bounds__(256) void prep_kernel(
    const float* __restrict__ w2, const float* __restrict__ w3,
    const float* __restrict__ w4, unsigned short* __restrict__ wb,
    const float* __restrict__ feat, float* __restrict__ zeroRegion,
    float* __restrict__ mom)
{
    const int bid = blockIdx.x;
    const int tid = threadIdx.x;
    if (bid < 320) {
        if (bid < 16) {   // zero stat2/3/4 (16384 floats)
            int z = bid * 1024 + tid * 4;
            *(f32x4*)(zeroRegion + z) = f32x4{0.f, 0.f, 0.f, 0.f};
        }
        int t = bid * 256 + tid;
        const float* src; int KD, ks; unsigned short* dst; int f;
        if (t < 16384)      { src = w2; KD = 128; ks = 2; dst = wb;         f = t; }
        else if (t < 49152) { src = w3; KD = 128; ks = 2; dst = wb + 16384; f = t - 16384; }
        else                { src = w4; KD = 256; ks = 3; dst = wb + 49152; f = t - 49152; }
        int e = f & 7, l = (f >> 3) & 63;
        int rest = f >> 9;
        int kb = rest & ((1 << ks) - 1);
        int cb = rest >> ks;
        dst[f] = f2b(src[(cb * 16 + (l & 15)) * KD + kb * 32 + (l >> 4) * 8 + e]);
        return;
    }
    // ---- feat moments: v[0..4]=S, v[5..19]=Msym (j<=k) ----
    __shared__ float red[80];
    const int mb = bid - 320;    // 0..117
    float v[20];
#pragma unroll
    for (int i = 0; i < 20; ++i) v[i] = 0.f;
#pragma unroll
    for (int i = 0; i < 4; ++i) {
        int row = mb * 1024 + i * 256 + tid;
        if (row < NN) {
            const float* fp = feat + (size_t)row * 5;
            float f0 = fp[0], f1 = fp[1], f2 = fp[2], f3 = fp[3], f4 = fp[4];
            v[0] += f0; v[1] += f1; v[2] += f2; v[3] += f3; v[4] += f4;
            v[5]  += f0*f0; v[6]  += f0*f1; v[7]  += f0*f2; v[8]  += f0*f3; v[9]  += f0*f4;
            v[10] += f1*f1; v[11] += f1*f2; v[12] += f1*f3; v[13] += f1*f4;
            v[14] += f2*f2; v[15] += f2*f3; v[16] += f2*f4;
            v[17] += f3*f3; v[18] += f3*f4; v[19] += f4*f4;
        }
    }
#pragma unroll
    for (int i = 0; i < 20; ++i) {
        v[i] += __shfl_xor(v[i], 1);  v[i] += __shfl_xor(v[i], 2);
        v[i] += __shfl_xor(v[i], 4);  v[i] += __shfl_xor(v[i], 8);
        v[i] += __shfl_xor(v[i], 16); v[i] += __shfl_xor(v[i], 32);
    }
    const int wv = tid >> 6, l = tid & 63;
    if (l == 0) {
#pragma unroll
        for (int i = 0; i < 20; ++i) red[wv * 20 + i] = v[i];
    }
    __syncthreads();
    if (tid < 20)
        mom[mb * 32 + tid] = red[tid] + red[20 + tid] + red[40 + tid] + red[60 + tid];
}

// ---------------------------------------------------------------------------
// gemm1: BN1 params from feat moments (exact); x1 = BN1relu(feat @ w1.T)
// in-block; y2 = x1 @ w2.T (MFMA); write y2 + stat2. 6 blocks/CU.
// ---------------------------------------------------------------------------
__global__ __launch_bounds__(256, 6) void gemm1_kernel(
    const float* __restrict__ feat, const float* __restrict__ w1,
    const float* __restrict__ g1, const float* __restrict__ b1,
    const float* __restrict__ mom,
    const unsigned short* __restrict__ Wf, unsigned short* __restrict__ Y,
    float* __restrict__ statsOut)
{
    __shared__ float featL[64 * 5];
    __shared__ float w1L[128 * 5];
    __shared__ float momL[20];
    __shared__ float scl[128], bia[128];
    __shared__ char  xs[17408];          // A-tile (16KB swizzled) / writeback scratch (pitch 272)
    __shared__ float red[256];

    const int tid = threadIdx.x;
    const int l = tid & 63, wv = tid >> 6;
    const int lm = l & 15, lg = l >> 4;
    const int rowbase = blockIdx.x * 64;
    const int cb0 = wv * 2;

    short8v bc[2], bn[2];
#pragma unroll
    for (int ni = 0; ni < 2; ++ni)
        bc[ni] = *(const short8v*)(Wf + ((size_t)((cb0 + ni) * 4) * 64 + l) * 8);

    if (tid < 64) {
        int row = rowbase + tid;
        if (row < NN) {
            const float* fp = feat + (size_t)row * 5;
#pragma unroll
            for (int k = 0; k < 5; ++k) featL[tid * 5 + k] = fp[k];
        } else {
#pragma unroll
            for (int k = 0; k < 5; ++k) featL[tid * 5 + k] = 0.f;
        }
    }
    if (tid < 160) *(f32x4*)(w1L + tid * 4) = *(const f32x4*)(w1 + tid * 4);
    if (tid < 20) {
        float s = 0.f;
#pragma unroll 16
        for (int j = 0; j < NMOMB; ++j) s += mom[j * 32 + tid];
        momL[tid] = s;
    }
    __syncthreads();
    if (tid < 128) {
        const float* wr = w1L + tid * 5;
        float mean = 0.f;
#pragma unroll
        for (int k = 0; k < 5; ++k) mean += wr[k] * momL[k];
        float e2 = 0.f;
        int idx = 5;
#pragma unroll
        for (int j = 0; j < 5; ++j)
#pragma unroll
            for (int k = j; k < 5; ++k) {
                float c = wr[j] * wr[k] * momL[idx++];
                e2 += (j == k) ? c : 2.f * c;
            }
        mean *= (1.0f / NN); e2 *= (1.0f / NN);
        float var = e2 - mean * mean;
        float sc  = g1[tid] * rsqrtf(var + EPSV);
        scl[tid] = sc;
        bia[tid] = b1[tid] - mean * sc;
    }
    __syncthreads();

    // x1 tile: thread owns 1 row x 32 cols (4 chunks of 8, stride 32)
    {
        int rloc = tid >> 2, c0 = (tid & 3) * 8;
        float f0 = featL[rloc*5], f1 = featL[rloc*5+1], f2 = featL[rloc*5+2],
              f3 = featL[rloc*5+3], f4 = featL[rloc*5+4];
#pragma unroll
        for (int u = 0; u < 4; ++u) {
            int cc = c0 + u * 32;
            ushort8v o;
#pragma unroll
            for (int e = 0; e < 8; ++e) {
                int c = cc + e;
                const float* wp = w1L + c * 5;
                float y = f0*wp[0] + f1*wp[1] + f2*wp[2] + f3*wp[3] + f4*wp[4];
                o[e] = f2b(fmaxf(y * scl[c] + bia[c], 0.f));
            }
            *(ushort8v*)(xs + rloc * 256 + ((cc * 2) ^ ((rloc & 7) << 4))) = o;
        }
    }
    __syncthreads();

    // MFMA with next-kk B prefetch
    f32x4 acc[4][2] = {};
#pragma unroll
    for (int kk = 0; kk < 4; ++kk) {
        if (kk < 3) {
#pragma unroll
            for (int ni = 0; ni < 2; ++ni)
                bn[ni] = *(const short8v*)(Wf + ((size_t)((cb0 + ni) * 4 + kk + 1) * 64 + l) * 8);
        }
        short8v a[4];
#pragma unroll
        for (int mi = 0; mi < 4; ++mi) {
            int row = mi * 16 + lm;
            a[mi] = *(const short8v*)(xs + row * 256 + ((kk * 64 + lg * 16) ^ ((row & 7) << 4)));
        }
#pragma unroll
        for (int ni = 0; ni < 2; ++ni)
#pragma unroll
            for (int mi = 0; mi < 4; ++mi)
                acc[mi][ni] = __builtin_amdgcn_mfma_f32_16x16x32_bf16(a[mi], bc[ni], acc[mi][ni], 0, 0, 0);
#pragma unroll
        for (int ni = 0; ni < 2; ++ni) bc[ni] = bn[ni];
    }

    // stat2 partials -> red
#pragma unroll
    for (int ni = 0; ni < 2; ++ni) {
        float s = 0.f, q = 0.f;
#pragma unroll
        for (int mi = 0; mi < 4; ++mi)
#pragma unroll
            for (int r = 0; r < 4; ++r) {
                int rowg = rowbase + mi * 16 + lg * 4 + r;
                float v = (rowg < NN) ? acc[mi][ni][r] : 0.f;
                s += v; q += v * v;
            }
        s += __shfl_xor(s, 16); s += __shfl_xor(s, 32);
        q += __shfl_xor(q, 16); q += __shfl_xor(q, 32);
        if (lg == 0) {
            int ch = (cb0 + ni) * 16 + lm;
            red[ch] = s; red[128 + ch] = q;
        }
    }
    __syncthreads();                     // xs reads done + red ready

    // scratch writes (pitch 272, 64x272=17408 fits xs) + stats atomics
#pragma unroll
    for (int mi = 0; mi < 4; ++mi)
#pragma unroll
        for (int ni = 0; ni < 2; ++ni)
#pragma unroll
            for (int r = 0; r < 4; ++r) {
                int rloc = mi * 16 + lg * 4 + r;
                int col = (cb0 + ni) * 16 + lm;
                *(unsigned short*)(xs + rloc * 272 + col * 2) = f2b(acc[mi][ni][r]);
            }
    if (tid < 128) {
        int slice = blockIdx.x & (NSLICE - 1);
        atomicAdd(statsOut + (size_t)slice * 256 + tid,       red[tid]);
        atomicAdd(statsOut + (size_t)slice * 256 + 128 + tid, red[128 + tid]);
    }
    __syncthreads();                     // scratch ready

    // coalesced y2 store: 4 threads/row x 64B
    {
        int rloc = tid >> 2;
        int u0 = (tid & 3) * 4;
        unsigned short* Yrow = Y + (size_t)(rowbase + rloc) * 128 + u0 * 8;
#pragma unroll
        for (int u = 0; u < 4; ++u)
            *(ushort8v*)(Yrow + u * 8) = *(const ushort8v*)(xs + rloc * 272 + (u0 + u) * 16);
    }
}

// ---------------------------------------------------------------------------
// gemm2s: stats-only y3 = BN2relu(y2) @ w3.T -> stat3. 6 blocks/CU.
// ---------------------------------------------------------------------------
__global__ __launch_bounds__(256, 6) void gemm2s_kernel(
    const unsigned short* __restrict__ X, const float* __restrict__ statsIn,
    const float* __restrict__ gIn, const float* __restrict__ bIn,
    const unsigned short* __restrict__ Wf, float* __restrict__ statsOut)
{
    __shared__ char  xs[16384];
    __shared__ float scl[128], bia[128];
    __shared__ float red[512];

    const int tid = threadIdx.x;
    const int l = tid & 63, wv = tid >> 6;
    const int lm = l & 15, lg = l >> 4;
    const int rowbase = blockIdx.x * 64;
    const int cb0 = wv * 4;

    ushort8v xr[4];
#pragma unroll
    for (int i = 0; i < 4; ++i) {
        int u = i * 256 + tid;
        xr[i] = *(const ushort8v*)(X + (size_t)(rowbase + (u >> 4)) * 128 + (u & 15) * 8);
    }
    if (tid < 128) {
        float s = 0.f, q = 0.f;
#pragma unroll 8
        for (int j = 0; j < NSLICE; ++j) {
            s += statsIn[j * 256 + tid];
            q += statsIn[j * 256 + 128 + tid];
        }
        float mean = s * (1.0f / NN);
        float var  = q * (1.0f / NN) - mean * mean;
        float sc   = gIn[tid] * rsqrtf(var + EPSV);
        scl[tid] = sc;
        bia[tid] = bIn[tid] - mean * sc;
    }
    __syncthreads();
#pragma unroll
    for (int i = 0; i < 4; ++i) {
        int u = i * 256 + tid;
        int row = u >> 4, cu = u & 15;
        f32x4 s0 = *(const f32x4*)(scl + cu * 8);
        f32x4 s1 = *(const f32x4*)(scl + cu * 8 + 4);
        f32x4 c0 = *(const f32x4*)(bia + cu * 8);
        f32x4 c1 = *(const f32x4*)(bia + cu * 8 + 4);
        ushort8v v = xr[i], o;
#pragma unroll
        for (int j = 0; j < 4; ++j) o[j]     = f2b(fmaxf(b2f(v[j])     * s0[j] + c0[j], 0.f));
#pragma unroll
        for (int j = 0; j < 4; ++j) o[4 + j] = f2b(fmaxf(b2f(v[4 + j]) * s1[j] + c1[j], 0.f));
        *(ushort8v*)(xs + row * 256 + ((cu * 16) ^ ((row & 7) << 4))) = o;
    }
    __syncthreads();

    f32x4 acc[4][4] = {};
    short8v bc[4], bn[4];
#pragma unroll
    for (int ni = 0; ni < 4; ++ni)
        bc[ni] = *(const short8v*)(Wf + ((size_t)((cb0 + ni) * 4) * 64 + l) * 8);
#pragma unroll
    for (int kk = 0; kk < 4; ++kk) {
        if (kk < 3) {
#pragma unroll
            for (int ni = 0; ni < 4; ++ni)
                bn[ni] = *(const short8v*)(Wf + ((size_t)((cb0 + ni) * 4 + kk + 1) * 64 + l) * 8);
        }
        short8v a[4];
#pragma unroll
        for (int mi = 0; mi < 4; ++mi) {
            int row = mi * 16 + lm;
            a[mi] = *(const short8v*)(xs + row * 256 + ((kk * 64 + lg * 16) ^ ((row & 7) << 4)));
        }
#pragma unroll
        for (int ni = 0; ni < 4; ++ni)
#pragma unroll
            for (int mi = 0; mi < 4; ++mi)
                acc[mi][ni] = __builtin_amdgcn_mfma_f32_16x16x32_bf16(a[mi], bc[ni], acc[mi][ni], 0, 0, 0);
#pragma unroll
        for (int ni = 0; ni < 4; ++ni) bc[ni] = bn[ni];
    }

#pragma unroll
    for (int ni = 0; ni < 4; ++ni) {
        float s = 0.f, q = 0.f;
#pragma unroll
        for (int mi = 0; mi < 4; ++mi)
#pragma unroll
            for (int r = 0; r < 4; ++r) {
                int rowg = rowbase + mi * 16 + lg * 4 + r;
                float v = (rowg < NN) ? acc[mi][ni][r] : 0.f;
                s += v; q += v * v;
            }
        s += __shfl_xor(s, 16); s += __shfl_xor(s, 32);
        q += __shfl_xor(q, 16); q += __shfl_xor(q, 32);
        if (lg == 0) {
            int ch = (cb0 + ni) * 16 + lm;
            red[ch] = s; red[256 + ch] = q;
        }
    }
    __syncthreads();
    {
        int slice = blockIdx.x & (NSLICE - 1);
        atomicAdd(statsOut + (size_t)slice * 512 + tid,       red[tid]);
        atomicAdd(statsOut + (size_t)slice * 512 + 256 + tid, red[256 + tid]);
    }
}

// ---------------------------------------------------------------------------
// gemm34: x2=BN2relu(y2) -> buf[0..16K); MFMA1; barrier; x3=BN3relu -> buf
// (pitch 520, aliased over the dead x2 tile); MFMA2; y4 + stat4.
// Union buffer: LDS 36608 => 4 blocks/CU.
// ---------------------------------------------------------------------------
__global__ __launch_bounds__(256, 4) void gemm34_kernel(
    const unsigned short* __restrict__ X,
    const float* __restrict__ stat2, const float* __restrict__ g2v, const float* __restrict__ b2v,
    const float* __restrict__ stat3, const float* __restrict__ g3v, const float* __restrict__ b3v,
    const unsigned short* __restrict__ Wf3, const unsigned short* __restrict__ Wf4,
    unsigned short* __restrict__ Y, float* __restrict__ statsOut)
{
    __shared__ char  buf[33280];         // x2 tile (16K swizzled) THEN x3 tile (pitch 520) THEN scratch (pitch 272)
    __shared__ float scl2[128], bia2[128], scl3[256], bia3[256];
    __shared__ float red[256];

    const int tid = threadIdx.x;
    const int l = tid & 63, wv = tid >> 6;
    const int lm = l & 15, lg = l >> 4;
    const int rowbase = blockIdx.x * 64;
    const int cb0 = wv * 4, cb02 = wv * 2;

    ushort8v xr[4];
#pragma unroll
    for (int i = 0; i < 4; ++i) {
        int u = i * 256 + tid;
        xr[i] = *(const ushort8v*)(X + (size_t)(rowbase + (u >> 4)) * 128 + (u & 15) * 8);
    }
    if (tid < 128) {
        float s = 0.f, q = 0.f;
#pragma unroll 8
        for (int j = 0; j < NSLICE; ++j) {
            s += stat2[j * 256 + tid];
            q += stat2[j * 256 + 128 + tid];
        }
        float mean = s * (1.0f / NN);
        float var  = q * (1.0f / NN) - mean * mean;
        float sc   = g2v[tid] * rsqrtf(var + EPSV);
        scl2[tid] = sc;
        bia2[tid] = b2v[tid] - mean * sc;
    }
    {
        float s = 0.f, q = 0.f;
#pragma unroll 8
        for (int j = 0; j < NSLICE; ++j) {
            s += stat3[j * 512 + tid];
            q += stat3[j * 512 + 256 + tid];
        }
        float mean = s * (1.0f / NN);
        float var  = q * (1.0f / NN) - mean * mean;
        float sc   = g3v[tid] * rsqrtf(var + EPSV);
        scl3[tid] = sc;
        bia3[tid] = b3v[tid] - mean * sc;
    }
    __syncthreads();
#pragma unroll
    for (int i = 0; i < 4; ++i) {
        int u = i * 256 + tid;
        int row = u >> 4, cu = u & 15;
        f32x4 s0 = *(const f32x4*)(scl2 + cu * 8);
        f32x4 s1 = *(const f32x4*)(scl2 + cu * 8 + 4);
        f32x4 c0 = *(const f32x4*)(bia2 + cu * 8);
        f32x4 c1 = *(const f32x4*)(bia2 + cu * 8 + 4);
        ushort8v v = xr[i], o;
#pragma unroll
        for (int j = 0; j < 4; ++j) o[j]     = f2b(fmaxf(b2f(v[j])     * s0[j] + c0[j], 0.f));
#pragma unroll
        for (int j = 0; j < 4; ++j) o[4 + j] = f2b(fmaxf(b2f(v[4 + j]) * s1[j] + c1[j], 0.f));
        *(ushort8v*)(buf + row * 256 + ((cu * 16) ^ ((row & 7) << 4))) = o;
    }
    __syncthreads();

    // MFMA1: y3 (KD=128, COUT=256) — reads x2 tile in buf
    f32x4 acc3[4][4] = {};
    {
        short8v bc3[4], bn3[4];
#pragma unroll
        for (int ni = 0; ni < 4; ++ni)
            bc3[ni] = *(const short8v*)(Wf3 + ((size_t)((cb0 + ni) * 4) * 64 + l) * 8);
#pragma unroll
        for (int kk = 0; kk < 4; ++kk) {
            if (kk < 3) {
#pragma unroll
                for (int ni = 0; ni < 4; ++ni)
                    bn3[ni] = *(const short8v*)(Wf3 + ((size_t)((cb0 + ni) * 4 + kk + 1) * 64 + l) * 8);
            }
            short8v a[4];
#pragma unroll
            for (int mi = 0; mi < 4; ++mi) {
                int row = mi * 16 + lm;
                a[mi] = *(const short8v*)(buf + row * 256 + ((kk * 64 + lg * 16) ^ ((row & 7) << 4)));
            }
#pragma unroll
            for (int ni = 0; ni < 4; ++ni)
#pragma unroll
                for (int mi = 0; mi < 4; ++mi)
                    acc3[mi][ni] = __builtin_amdgcn_mfma_f32_16x16x32_bf16(a[mi], bc3[ni], acc3[mi][ni], 0, 0, 0);
#pragma unroll
            for (int ni = 0; ni < 4; ++ni) bc3[ni] = bn3[ni];
        }
    }
    __syncthreads();                     // ALL waves done reading x2 tile (buf reused next)

    // x3 = BN3relu(y3) -> buf (pitch 520B); prefetch MFMA2 kk=0 B frags
    short8v bc4[2], bn4[2];
#pragma unroll
    for (int ni = 0; ni < 2; ++ni)
        bc4[ni] = *(const short8v*)(Wf4 + ((size_t)((cb02 + ni) * 8) * 64 + l) * 8);
#pragma unroll
    for (int ni = 0; ni < 4; ++ni) {
        int col = (cb0 + ni) * 16 + lm;
        float sc = scl3[col], bi = bia3[col];
#pragma unroll
        for (int mi = 0; mi < 4; ++mi)
#pragma unroll
            for (int r = 0; r < 4; ++r) {
                int row = mi * 16 + lg * 4 + r;
                *(unsigned short*)(buf + row * 520 + col * 2) =
                    f2b(fmaxf(acc3[mi][ni][r] * sc + bi, 0.f));
            }
    }
    __syncthreads();

    // MFMA2: y4 (K=256, COUT=128)
    f32x4 acc4[4][2] = {};
#pragma unroll
    for (int kk = 0; kk < 8; ++kk) {
        if (kk < 7) {
#pragma unroll
            for (int ni = 0; ni < 2; ++ni)
                bn4[ni] = *(const short8v*)(Wf4 + ((size_t)((cb02 + ni) * 8 + kk + 1) * 64 + l) * 8);
        }
        short8v a[4];
#pragma unroll
        for (int mi = 0; mi < 4; ++mi) {
            int row = mi * 16 + lm;
            a[mi] = *(const short8v*)(buf + row * 520 + (kk * 64 + lg * 16));
        }
#pragma unroll
        for (int ni = 0; ni < 2; ++ni)
#pragma unroll
            for (int mi = 0; mi < 4; ++mi)
                acc4[mi][ni] = __builtin_amdgcn_mfma_f32_16x16x32_bf16(a[mi], bc4[ni], acc4[mi][ni], 0, 0, 0);
#pragma unroll
        for (int ni = 0; ni < 2; ++ni) bc4[ni] = bn4[ni];
    }

    // stat4 partials
#pragma unroll
    for (int ni = 0; ni < 2; ++ni) {
        float s = 0.f, q = 0.f;
#pragma unroll
        for (int mi = 0; mi < 4; ++mi)
#pragma unroll
            for (int r = 0; r < 4; ++r) {
                int rowg = rowbase + mi * 16 + lg * 4 + r;
                float v = (rowg < NN) ? acc4[mi][ni][r] : 0.f;
                s += v; q += v * v;
            }
        s += __shfl_xor(s, 16); s += __shfl_xor(s, 32);
        q += __shfl_xor(q, 16); q += __shfl_xor(q, 32);
        if (lg == 0) {
            int ch = (cb02 + ni) * 16 + lm;
            red[ch] = s; red[128 + ch] = q;
        }
    }
    __syncthreads();                     // x3 reads done + red ready

    // scratch writes into buf (pitch 272, 17408 <= 33280) + stats atomics
#pragma unroll
    for (int mi = 0; mi < 4; ++mi)
#pragma unroll
        for (int ni = 0; ni < 2; ++ni)
#pragma unroll
            for (int r = 0; r < 4; ++r) {
                int rloc = mi * 16 + lg * 4 + r;
                int col = (cb02 + ni) * 16 + lm;
                *(unsigned short*)(buf + rloc * 272 + col * 2) = f2b(acc4[mi][ni][r]);
            }
    if (tid < 128) {
        int slice = blockIdx.x & (NSLICE - 1);
        atomicAdd(statsOut + (size_t)slice * 256 + tid,       red[tid]);
        atomicAdd(statsOut + (size_t)slice * 256 + 128 + tid, red[128 + tid]);
    }
    __syncthreads();                     // scratch ready

    // coalesced y4 store
    {
        int rloc = tid >> 2;
        int u0 = (tid & 3) * 4;
        unsigned short* Yrow = Y + (size_t)(rowbase + rloc) * 128 + u0 * 8;
#pragma unroll
        for (int u = 0; u < 4; ++u)
            *(ushort8v*)(Yrow + u * 8) = *(const ushort8v*)(buf + rloc * 272 + (u0 + u) * 16);
    }
}

// ---------------------------------------------------------------------------
// K5: x5 = relu( BN4(y4) + relu(BN2(y2)) ); logits = x5 @ w_out.T + b_out.
// 938 blocks x 128 rows; wT XOR-swizzled; 8 blocks/CU (BW-bound, max TLP).
// ---------------------------------------------------------------------------
__global__ __launch_bounds__(256, 8) void k5_kernel(
    const unsigned short* __restrict__ y2, const unsigned short* __restrict__ y4,
    const float* __restrict__ stat2, const float* __restrict__ g2, const float* __restrict__ b2,
    const float* __restrict__ stat4, const float* __restrict__ g4, const float* __restrict__ b4,
    const float* __restrict__ w_out, const float* __restrict__ b_out,
    float* __restrict__ out)
{
    __shared__ float wT[128 * 8];
    __shared__ float sc2[128], bi2[128], sc4[128], bi4[128], bo[8];
    const int tid = threadIdx.x;

    if (tid < 128) {
        float s2 = 0.f, q2 = 0.f, s4 = 0.f, q4 = 0.f;
#pragma unroll 8
        for (int j = 0; j < NSLICE; ++j) {
            s2 += stat2[j * 256 + tid];       q2 += stat2[j * 256 + 128 + tid];
            s4 += stat4[j * 256 + tid];       q4 += stat4[j * 256 + 128 + tid];
        }
        float m2 = s2 * (1.0f / NN);
        float v2 = q2 * (1.0f / NN) - m2 * m2;
        float t2 = g2[tid] * rsqrtf(v2 + EPSV);
        sc2[tid] = t2; bi2[tid] = b2[tid] - m2 * t2;
        float m4 = s4 * (1.0f / NN);
        float v4 = q4 * (1.0f / NN) - m4 * m4;
        float t4 = g4[tid] * rsqrtf(v4 + EPSV);
        sc4[tid] = t4; bi4[tid] = b4[tid] - m4 * t4;
    }
    for (int i = tid; i < 1024; i += 256) {
        float val = w_out[(i & 7) * 128 + (i >> 3)];
        int swz = (((i >> 2) ^ ((i >> 7) & 7)) << 2) | (i & 3);
        wT[swz] = val;
    }
    if (tid < 8) bo[tid] = b_out[tid];
    __syncthreads();

    const int l = tid & 63, wv = tid >> 6;
    const int sub = l & 7, rl = l >> 3;

#pragma unroll
    for (int gi = 0; gi < 4; ++gi) {
        int row = blockIdx.x * 128 + gi * 32 + wv * 8 + rl;
        if (row >= NN) continue;

        const ushort8v* p2 = (const ushort8v*)(y2 + (size_t)row * 128 + sub * 16);
        const ushort8v* p4 = (const ushort8v*)(y4 + (size_t)row * 128 + sub * 16);

        float p[8];
#pragma unroll
        for (int o = 0; o < 8; ++o) p[o] = 0.f;

#pragma unroll
        for (int jj = 0; jj < 2; ++jj) {
            ushort8v a2 = p2[jj];
            ushort8v a4 = p4[jj];
#pragma unroll
            for (int e = 0; e < 8; ++e) {
                int c = sub * 16 + jj * 8 + e;
                float i2 = fmaxf(b2f(a2[e]) * sc2[c] + bi2[c], 0.f);
                float x4 = b2f(a4[e]) * sc4[c] + bi4[c];
                float x5 = fmaxf(x4 + i2, 0.f);
                f32x4 wa = *(const f32x4*)(wT + (((c * 2)     ^ sub) << 2));
                f32x4 wb = *(const f32x4*)(wT + (((c * 2 + 1) ^ sub) << 2));
                p[0] += x5 * wa[0]; p[1] += x5 * wa[1]; p[2] += x5 * wa[2]; p[3] += x5 * wa[3];
                p[4] += x5 * wb[0]; p[5] += x5 * wb[1]; p[6] += x5 * wb[2]; p[7] += x5 * wb[3];
            }
        }
#pragma unroll
        for (int o = 0; o < 8; ++o) {
            p[o] += __shfl_xor(p[o], 1);
            p[o] += __shfl_xor(p[o], 2);
            p[o] += __shfl_xor(p[o], 4);
        }
        out[(size_t)row * 8 + sub] = p[sub] + bo[sub];
    }
}

// ---------------------------------------------------------------------------
extern "C" void kernel_launch(void* const* d_in, const int* in_sizes, int n_in,
                              void* d_out, int out_size, void* d_ws, size_t ws_size,
                              hipStream_t stream)
{
    const float* feat  = (const float*)d_in[0];
    // d_in[1] coord, d_in[2] knn_idx, d_in[3] offset: dead code in reference
    const float* w1    = (const float*)d_in[4];
    const float* g1    = (const float*)d_in[5];
    const float* b1    = (const float*)d_in[6];
    const float* w2    = (const float*)d_in[7];
    const float* g2    = (const float*)d_in[8];
    const float* b2    = (const float*)d_in[9];
    const float* w3    = (const float*)d_in[10];
    const float* g3    = (const float*)d_in[11];
    const float* b3    = (const float*)d_in[12];
    const float* w4    = (const float*)d_in[13];
    const float* g4    = (const float*)d_in[14];
    const float* b4    = (const float*)d_in[15];
    const float* w_out = (const float*)d_in[16];
    const float* b_out = (const float*)d_in[17];

    char* ws = (char*)d_ws;
    const size_t sz128 = (size_t)NP * 128 * 2;   // bf16 N x 128
    unsigned short* y2 = (unsigned short*)(ws);
    unsigned short* y4 = (unsigned short*)(ws + sz128);
    float* stats       = (float*)(ws + 2 * sz128);
    // mom [118][32] @0 (pad to 3840), stat2 [16][2][128] @3840,
    // stat3 [16][2][256] @7936, stat4 [16][2][128] @16128
    float* mom   = stats;
    float* stat2 = stats + 3840;
    float* stat3 = stats + 7936;
    float* stat4 = stats + 16128;
    unsigned short* wb = (unsigned short*)(stats + 20224);  // 81920 bf16 frag weights

    prep_kernel<<<dim3(320 + NMOMB), 256, 0, stream>>>(w2, w3, w4, wb, feat,
                                                       stat2 /*zero region*/, mom);
    gemm1_kernel<<<dim3(1876), 256, 0, stream>>>(feat, w1, g1, b1, mom, wb, y2, stat2);
    gemm2s_kernel<<<dim3(1876), 256, 0, stream>>>(y2, stat2, g2, b2, wb + 16384, stat3);
    gemm34_kernel<<<dim3(1876), 256, 0, stream>>>(y2, stat2, g2, b2, stat3, g3, b3,
                                                  wb + 16384, wb + 49152, y4, stat4);
    k5_kernel<<<dim3(938), 256, 0, stream>>>(y2, y4, stat2, g2, b2, stat4, g4, b4,
                                             w_out, b_out, (float*)d_out);
}

// Round 24
// 106.764 us; speedup vs baseline: 1.4664x; 1.4664x over previous
//
#include <hip/hip_runtime.h>
#include <hip/hip_bf16.h>

#define NN   120000
#define NP   120064   // 1876 * 64, padded rows
#define EPSV 1e-5f
#define NSLICE 16
#define NMOMB 118     // moment blocks (118 * 1024 rows >= NN)

typedef __attribute__((ext_vector_type(8))) short          short8v;   // bf16 MFMA frag
typedef __attribute__((ext_vector_type(8))) unsigned short ushort8v;
typedef __attribute__((ext_vector_type(4))) float          f32x4;

__device__ __forceinline__ float b2f(unsigned short u) {
    union { unsigned int i; float f; } x; x.i = ((unsigned int)u) << 16; return x.f;
}
__device__ __forceinline__ unsigned short f2b(float f) {
    __hip_bfloat16 h = __float2bfloat16(f);   // RTNE; pairs fuse to v_cvt_pk_bf16_f32
    return *reinterpret_cast<unsigned short*>(&h);
}

// ---------------------------------------------------------------------------
// prep: blocks [0,320): w2/w3/w4 -> bf16 fragment-linear (blocks 0..15 also
//       zero the stat2/3/4 region first). blocks [320,438): feat moments.
// ---------------------------------------------------------------------------
__global__ __launch_bounds__(256) void prep_kernel(
    const float* __restrict__ w2, const float* __restrict__ w3,
    const float* __restrict__ w4, unsigned short* __restrict__ wb,
    const float* __restrict__ feat, float* __restrict__ zeroRegion,
    float* __restrict__ mom)
{
    const int bid = blockIdx.x;
    const int tid = threadIdx.x;
    if (bid < 320) {
        if (bid < 16) {   // zero stat2/3/4 (16384 floats)
            int z = bid * 1024 + tid * 4;
            *(f32x4*)(zeroRegion + z) = f32x4{0.f, 0.f, 0.f, 0.f};
        }
        int t = bid * 256 + tid;
        const float* src; int KD, ks; unsigned short* dst; int f;
        if (t < 16384)      { src = w2; KD = 128; ks = 2; dst = wb;         f = t; }
        else if (t < 49152) { src = w3; KD = 128; ks = 2; dst = wb + 16384; f = t - 16384; }
        else                { src = w4; KD = 256; ks = 3; dst = wb + 49152; f = t - 49152; }
        int e = f & 7, l = (f >> 3) & 63;
        int rest = f >> 9;
        int kb = rest & ((1 << ks) - 1);
        int cb = rest >> ks;
        dst[f] = f2b(src[(cb * 16 + (l & 15)) * KD + kb * 32 + (l >> 4) * 8 + e]);
        return;
    }
    // ---- feat moments: v[0..4]=S, v[5..19]=Msym (j<=k) ----
    __shared__ float red[80];
    const int mb = bid - 320;    // 0..117
    float v[20];
#pragma unroll
    for (int i = 0; i < 20; ++i) v[i] = 0.f;
#pragma unroll
    for (int i = 0; i < 4; ++i) {
        int row = mb * 1024 + i * 256 + tid;
        if (row < NN) {
            const float* fp = feat + (size_t)row * 5;
            float f0 = fp[0], f1 = fp[1], f2 = fp[2], f3 = fp[3], f4 = fp[4];
            v[0] += f0; v[1] += f1; v[2] += f2; v[3] += f3; v[4] += f4;
            v[5]  += f0*f0; v[6]  += f0*f1; v[7]  += f0*f2; v[8]  += f0*f3; v[9]  += f0*f4;
            v[10] += f1*f1; v[11] += f1*f2; v[12] += f1*f3; v[13] += f1*f4;
            v[14] += f2*f2; v[15] += f2*f3; v[16] += f2*f4;
            v[17] += f3*f3; v[18] += f3*f4; v[19] += f4*f4;
        }
    }
#pragma unroll
    for (int i = 0; i < 20; ++i) {
        v[i] += __shfl_xor(v[i], 1);  v[i] += __shfl_xor(v[i], 2);
        v[i] += __shfl_xor(v[i], 4);  v[i] += __shfl_xor(v[i], 8);
        v[i] += __shfl_xor(v[i], 16); v[i] += __shfl_xor(v[i], 32);
    }
    const int wv = tid >> 6, l = tid & 63;
    if (l == 0) {
#pragma unroll
        for (int i = 0; i < 20; ++i) red[wv * 20 + i] = v[i];
    }
    __syncthreads();
    if (tid < 20)
        mom[mb * 32 + tid] = red[tid] + red[20 + tid] + red[40 + tid] + red[60 + tid];
}

// ---------------------------------------------------------------------------
// gemm1: BN1 params from feat moments (exact); x1 = BN1relu(feat @ w1.T)
// in-block; y2 = x1 @ w2.T (MFMA); write y2 + stat2.
// ---------------------------------------------------------------------------
__global__ __launch_bounds__(256, 4) void gemm1_kernel(
    const float* __restrict__ feat, const float* __restrict__ w1,
    const float* __restrict__ g1, const float* __restrict__ b1,
    const float* __restrict__ mom,
    const unsigned short* __restrict__ Wf, unsigned short* __restrict__ Y,
    float* __restrict__ statsOut)
{
    __shared__ float featL[64 * 5];
    __shared__ float w1L[128 * 5];
    __shared__ float momL[20];
    __shared__ float scl[128], bia[128];
    __shared__ char  xs[17408];          // A-tile (16KB swizzled) / writeback scratch (pitch 272)
    __shared__ float red[256];

    const int tid = threadIdx.x;
    const int l = tid & 63, wv = tid >> 6;
    const int lm = l & 15, lg = l >> 4;
    const int rowbase = blockIdx.x * 64;
    const int cb0 = wv * 2;

    short8v bc[2], bn[2];
#pragma unroll
    for (int ni = 0; ni < 2; ++ni)
        bc[ni] = *(const short8v*)(Wf + ((size_t)((cb0 + ni) * 4) * 64 + l) * 8);

    if (tid < 64) {
        int row = rowbase + tid;
        if (row < NN) {
            const float* fp = feat + (size_t)row * 5;
#pragma unroll
            for (int k = 0; k < 5; ++k) featL[tid * 5 + k] = fp[k];
        } else {
#pragma unroll
            for (int k = 0; k < 5; ++k) featL[tid * 5 + k] = 0.f;
        }
    }
    if (tid < 160) *(f32x4*)(w1L + tid * 4) = *(const f32x4*)(w1 + tid * 4);
    if (tid < 20) {
        float s = 0.f;
#pragma unroll 16
        for (int j = 0; j < NMOMB; ++j) s += mom[j * 32 + tid];
        momL[tid] = s;
    }
    __syncthreads();
    if (tid < 128) {
        const float* wr = w1L + tid * 5;
        float mean = 0.f;
#pragma unroll
        for (int k = 0; k < 5; ++k) mean += wr[k] * momL[k];
        float e2 = 0.f;
        int idx = 5;
#pragma unroll
        for (int j = 0; j < 5; ++j)
#pragma unroll
            for (int k = j; k < 5; ++k) {
                float c = wr[j] * wr[k] * momL[idx++];
                e2 += (j == k) ? c : 2.f * c;
            }
        mean *= (1.0f / NN); e2 *= (1.0f / NN);
        float var = e2 - mean * mean;
        float sc  = g1[tid] * rsqrtf(var + EPSV);
        scl[tid] = sc;
        bia[tid] = b1[tid] - mean * sc;
    }
    __syncthreads();

    // x1 tile: thread owns 1 row x 32 cols (4 chunks of 8, stride 32)
    {
        int rloc = tid >> 2, c0 = (tid & 3) * 8;
        float f0 = featL[rloc*5], f1 = featL[rloc*5+1], f2 = featL[rloc*5+2],
              f3 = featL[rloc*5+3], f4 = featL[rloc*5+4];
#pragma unroll
        for (int u = 0; u < 4; ++u) {
            int cc = c0 + u * 32;
            ushort8v o;
#pragma unroll
            for (int e = 0; e < 8; ++e) {
                int c = cc + e;
                const float* wp = w1L + c * 5;
                float y = f0*wp[0] + f1*wp[1] + f2*wp[2] + f3*wp[3] + f4*wp[4];
                o[e] = f2b(fmaxf(y * scl[c] + bia[c], 0.f));
            }
            *(ushort8v*)(xs + rloc * 256 + ((cc * 2) ^ ((rloc & 7) << 4))) = o;
        }
    }
    __syncthreads();

    // MFMA with next-kk B prefetch
    f32x4 acc[4][2] = {};
#pragma unroll
    for (int kk = 0; kk < 4; ++kk) {
        if (kk < 3) {
#pragma unroll
            for (int ni = 0; ni < 2; ++ni)
                bn[ni] = *(const short8v*)(Wf + ((size_t)((cb0 + ni) * 4 + kk + 1) * 64 + l) * 8);
        }
        short8v a[4];
#pragma unroll
        for (int mi = 0; mi < 4; ++mi) {
            int row = mi * 16 + lm;
            a[mi] = *(const short8v*)(xs + row * 256 + ((kk * 64 + lg * 16) ^ ((row & 7) << 4)));
        }
#pragma unroll
        for (int ni = 0; ni < 2; ++ni)
#pragma unroll
            for (int mi = 0; mi < 4; ++mi)
                acc[mi][ni] = __builtin_amdgcn_mfma_f32_16x16x32_bf16(a[mi], bc[ni], acc[mi][ni], 0, 0, 0);
#pragma unroll
        for (int ni = 0; ni < 2; ++ni) bc[ni] = bn[ni];
    }

    // stat2 partials -> red
#pragma unroll
    for (int ni = 0; ni < 2; ++ni) {
        float s = 0.f, q = 0.f;
#pragma unroll
        for (int mi = 0; mi < 4; ++mi)
#pragma unroll
            for (int r = 0; r < 4; ++r) {
                int rowg = rowbase + mi * 16 + lg * 4 + r;
                float v = (rowg < NN) ? acc[mi][ni][r] : 0.f;
                s += v; q += v * v;
            }
        s += __shfl_xor(s, 16); s += __shfl_xor(s, 32);
        q += __shfl_xor(q, 16); q += __shfl_xor(q, 32);
        if (lg == 0) {
            int ch = (cb0 + ni) * 16 + lm;
            red[ch] = s; red[128 + ch] = q;
        }
    }
    __syncthreads();                     // xs reads done + red ready

    // scratch writes (pitch 272, 64x272=17408 fits xs) + stats atomics
#pragma unroll
    for (int mi = 0; mi < 4; ++mi)
#pragma unroll
        for (int ni = 0; ni < 2; ++ni)
#pragma unroll
            for (int r = 0; r < 4; ++r) {
                int rloc = mi * 16 + lg * 4 + r;
                int col = (cb0 + ni) * 16 + lm;
                *(unsigned short*)(xs + rloc * 272 + col * 2) = f2b(acc[mi][ni][r]);
            }
    if (tid < 128) {
        int slice = blockIdx.x & (NSLICE - 1);
        atomicAdd(statsOut + (size_t)slice * 256 + tid,       red[tid]);
        atomicAdd(statsOut + (size_t)slice * 256 + 128 + tid, red[128 + tid]);
    }
    __syncthreads();                     // scratch ready

    // coalesced y2 store: 4 threads/row x 64B
    {
        int rloc = tid >> 2;
        int u0 = (tid & 3) * 4;
        unsigned short* Yrow = Y + (size_t)(rowbase + rloc) * 128 + u0 * 8;
#pragma unroll
        for (int u = 0; u < 4; ++u)
            *(ushort8v*)(Yrow + u * 8) = *(const ushort8v*)(xs + rloc * 272 + (u0 + u) * 16);
    }
}

// ---------------------------------------------------------------------------
// gemm2s: stats-only y3 = BN2relu(y2) @ w3.T -> stat3. (round-8 body)
// ---------------------------------------------------------------------------
__global__ __launch_bounds__(256, 4) void gemm2s_kernel(
    const unsigned short* __restrict__ X, const float* __restrict__ statsIn,
    const float* __restrict__ gIn, const float* __restrict__ bIn,
    const unsigned short* __restrict__ Wf, float* __restrict__ statsOut)
{
    __shared__ char  xs[16384];
    __shared__ float scl[128], bia[128];
    __shared__ float red[512];

    const int tid = threadIdx.x;
    const int l = tid & 63, wv = tid >> 6;
    const int lm = l & 15, lg = l >> 4;
    const int rowbase = blockIdx.x * 64;
    const int cb0 = wv * 4;

    ushort8v xr[4];
#pragma unroll
    for (int i = 0; i < 4; ++i) {
        int u = i * 256 + tid;
        xr[i] = *(const ushort8v*)(X + (size_t)(rowbase + (u >> 4)) * 128 + (u & 15) * 8);
    }
    if (tid < 128) {
        float s = 0.f, q = 0.f;
#pragma unroll 8
        for (int j = 0; j < NSLICE; ++j) {
            s += statsIn[j * 256 + tid];
            q += statsIn[j * 256 + 128 + tid];
        }
        float mean = s * (1.0f / NN);
        float var  = q * (1.0f / NN) - mean * mean;
        float sc   = gIn[tid] * rsqrtf(var + EPSV);
        scl[tid] = sc;
        bia[tid] = bIn[tid] - mean * sc;
    }
    __syncthreads();
#pragma unroll
    for (int i = 0; i < 4; ++i) {
        int u = i * 256 + tid;
        int row = u >> 4, cu = u & 15;
        f32x4 s0 = *(const f32x4*)(scl + cu * 8);
        f32x4 s1 = *(const f32x4*)(scl + cu * 8 + 4);
        f32x4 c0 = *(const f32x4*)(bia + cu * 8);
        f32x4 c1 = *(const f32x4*)(bia + cu * 8 + 4);
        ushort8v v = xr[i], o;
#pragma unroll
        for (int j = 0; j < 4; ++j) o[j]     = f2b(fmaxf(b2f(v[j])     * s0[j] + c0[j], 0.f));
#pragma unroll
        for (int j = 0; j < 4; ++j) o[4 + j] = f2b(fmaxf(b2f(v[4 + j]) * s1[j] + c1[j], 0.f));
        *(ushort8v*)(xs + row * 256 + ((cu * 16) ^ ((row & 7) << 4))) = o;
    }
    __syncthreads();

    f32x4 acc[4][4] = {};
    short8v bc[4], bn[4];
#pragma unroll
    for (int ni = 0; ni < 4; ++ni)
        bc[ni] = *(const short8v*)(Wf + ((size_t)((cb0 + ni) * 4) * 64 + l) * 8);
#pragma unroll
    for (int kk = 0; kk < 4; ++kk) {
        if (kk < 3) {
#pragma unroll
            for (int ni = 0; ni < 4; ++ni)
                bn[ni] = *(const short8v*)(Wf + ((size_t)((cb0 + ni) * 4 + kk + 1) * 64 + l) * 8);
        }
        short8v a[4];
#pragma unroll
        for (int mi = 0; mi < 4; ++mi) {
            int row = mi * 16 + lm;
            a[mi] = *(const short8v*)(xs + row * 256 + ((kk * 64 + lg * 16) ^ ((row & 7) << 4)));
        }
#pragma unroll
        for (int ni = 0; ni < 4; ++ni)
#pragma unroll
            for (int mi = 0; mi < 4; ++mi)
                acc[mi][ni] = __builtin_amdgcn_mfma_f32_16x16x32_bf16(a[mi], bc[ni], acc[mi][ni], 0, 0, 0);
#pragma unroll
        for (int ni = 0; ni < 4; ++ni) bc[ni] = bn[ni];
    }

#pragma unroll
    for (int ni = 0; ni < 4; ++ni) {
        float s = 0.f, q = 0.f;
#pragma unroll
        for (int mi = 0; mi < 4; ++mi)
#pragma unroll
            for (int r = 0; r < 4; ++r) {
                int rowg = rowbase + mi * 16 + lg * 4 + r;
                float v = (rowg < NN) ? acc[mi][ni][r] : 0.f;
                s += v; q += v * v;
            }
        s += __shfl_xor(s, 16); s += __shfl_xor(s, 32);
        q += __shfl_xor(q, 16); q += __shfl_xor(q, 32);
        if (lg == 0) {
            int ch = (cb0 + ni) * 16 + lm;
            red[ch] = s; red[256 + ch] = q;
        }
    }
    __syncthreads();
    {
        int slice = blockIdx.x & (NSLICE - 1);
        atomicAdd(statsOut + (size_t)slice * 512 + tid,       red[tid]);
        atomicAdd(statsOut + (size_t)slice * 512 + 256 + tid, red[256 + tid]);
    }
}

// ---------------------------------------------------------------------------
// gemm34: x2=BN2relu(y2) -> buf[0..16K); MFMA1; barrier; x3=BN3relu -> buf
// (pitch 520, aliased over the dead x2 tile); MFMA2; y4 + stat4.
// Union buffer: LDS 36608 => 4 blocks/CU.
// ---------------------------------------------------------------------------
__global__ __launch_bounds__(256, 4) void gemm34_kernel(
    const unsigned short* __restrict__ X,
    const float* __restrict__ stat2, const float* __restrict__ g2v, const float* __restrict__ b2v,
    const float* __restrict__ stat3, const float* __restrict__ g3v, const float* __restrict__ b3v,
    const unsigned short* __restrict__ Wf3, const unsigned short* __restrict__ Wf4,
    unsigned short* __restrict__ Y, float* __restrict__ statsOut)
{
    __shared__ char  buf[33280];         // x2 tile (16K swizzled) THEN x3 tile (pitch 520) THEN scratch (pitch 272)
    __shared__ float scl2[128], bia2[128], scl3[256], bia3[256];
    __shared__ float red[256];

    const int tid = threadIdx.x;
    const int l = tid & 63, wv = tid >> 6;
    const int lm = l & 15, lg = l >> 4;
    const int rowbase = blockIdx.x * 64;
    const int cb0 = wv * 4, cb02 = wv * 2;

    ushort8v xr[4];
#pragma unroll
    for (int i = 0; i < 4; ++i) {
        int u = i * 256 + tid;
        xr[i] = *(const ushort8v*)(X + (size_t)(rowbase + (u >> 4)) * 128 + (u & 15) * 8);
    }
    if (tid < 128) {
        float s = 0.f, q = 0.f;
#pragma unroll 8
        for (int j = 0; j < NSLICE; ++j) {
            s += stat2[j * 256 + tid];
            q += stat2[j * 256 + 128 + tid];
        }
        float mean = s * (1.0f / NN);
        float var  = q * (1.0f / NN) - mean * mean;
        float sc   = g2v[tid] * rsqrtf(var + EPSV);
        scl2[tid] = sc;
        bia2[tid] = b2v[tid] - mean * sc;
    }
    {
        float s = 0.f, q = 0.f;
#pragma unroll 8
        for (int j = 0; j < NSLICE; ++j) {
            s += stat3[j * 512 + tid];
            q += stat3[j * 512 + 256 + tid];
        }
        float mean = s * (1.0f / NN);
        float var  = q * (1.0f / NN) - mean * mean;
        float sc   = g3v[tid] * rsqrtf(var + EPSV);
        scl3[tid] = sc;
        bia3[tid] = b3v[tid] - mean * sc;
    }
    __syncthreads();
#pragma unroll
    for (int i = 0; i < 4; ++i) {
        int u = i * 256 + tid;
        int row = u >> 4, cu = u & 15;
        f32x4 s0 = *(const f32x4*)(scl2 + cu * 8);
        f32x4 s1 = *(const f32x4*)(scl2 + cu * 8 + 4);
        f32x4 c0 = *(const f32x4*)(bia2 + cu * 8);
        f32x4 c1 = *(const f32x4*)(bia2 + cu * 8 + 4);
        ushort8v v = xr[i], o;
#pragma unroll
        for (int j = 0; j < 4; ++j) o[j]     = f2b(fmaxf(b2f(v[j])     * s0[j] + c0[j], 0.f));
#pragma unroll
        for (int j = 0; j < 4; ++j) o[4 + j] = f2b(fmaxf(b2f(v[4 + j]) * s1[j] + c1[j], 0.f));
        *(ushort8v*)(buf + row * 256 + ((cu * 16) ^ ((row & 7) << 4))) = o;
    }
    __syncthreads();

    // MFMA1: y3 (KD=128, COUT=256) — reads x2 tile in buf
    f32x4 acc3[4][4] = {};
    {
        short8v bc3[4], bn3[4];
#pragma unroll
        for (int ni = 0; ni < 4; ++ni)
            bc3[ni] = *(const short8v*)(Wf3 + ((size_t)((cb0 + ni) * 4) * 64 + l) * 8);
#pragma unroll
        for (int kk = 0; kk < 4; ++kk) {
            if (kk < 3) {
#pragma unroll
                for (int ni = 0; ni < 4; ++ni)
                    bn3[ni] = *(const short8v*)(Wf3 + ((size_t)((cb0 + ni) * 4 + kk + 1) * 64 + l) * 8);
            }
            short8v a[4];
#pragma unroll
            for (int mi = 0; mi < 4; ++mi) {
                int row = mi * 16 + lm;
                a[mi] = *(const short8v*)(buf + row * 256 + ((kk * 64 + lg * 16) ^ ((row & 7) << 4)));
            }
#pragma unroll
            for (int ni = 0; ni < 4; ++ni)
#pragma unroll
                for (int mi = 0; mi < 4; ++mi)
                    acc3[mi][ni] = __builtin_amdgcn_mfma_f32_16x16x32_bf16(a[mi], bc3[ni], acc3[mi][ni], 0, 0, 0);
#pragma unroll
            for (int ni = 0; ni < 4; ++ni) bc3[ni] = bn3[ni];
        }
    }
    __syncthreads();                     // ALL waves done reading x2 tile (buf reused next)

    // x3 = BN3relu(y3) -> buf (pitch 520B); prefetch MFMA2 kk=0 B frags
    short8v bc4[2], bn4[2];
#pragma unroll
    for (int ni = 0; ni < 2; ++ni)
        bc4[ni] = *(const short8v*)(Wf4 + ((size_t)((cb02 + ni) * 8) * 64 + l) * 8);
#pragma unroll
    for (int ni = 0; ni < 4; ++ni) {
        int col = (cb0 + ni) * 16 + lm;
        float sc = scl3[col], bi = bia3[col];
#pragma unroll
        for (int mi = 0; mi < 4; ++mi)
#pragma unroll
            for (int r = 0; r < 4; ++r) {
                int row = mi * 16 + lg * 4 + r;
                *(unsigned short*)(buf + row * 520 + col * 2) =
                    f2b(fmaxf(acc3[mi][ni][r] * sc + bi, 0.f));
            }
    }
    __syncthreads();

    // MFMA2: y4 (K=256, COUT=128)
    f32x4 acc4[4][2] = {};
#pragma unroll
    for (int kk = 0; kk < 8; ++kk) {
        if (kk < 7) {
#pragma unroll
            for (int ni = 0; ni < 2; ++ni)
                bn4[ni] = *(const short8v*)(Wf4 + ((size_t)((cb02 + ni) * 8 + kk + 1) * 64 + l) * 8);
        }
        short8v a[4];
#pragma unroll
        for (int mi = 0; mi < 4; ++mi) {
            int row = mi * 16 + lm;
            a[mi] = *(const short8v*)(buf + row * 520 + (kk * 64 + lg * 16));
        }
#pragma unroll
        for (int ni = 0; ni < 2; ++ni)
#pragma unroll
            for (int mi = 0; mi < 4; ++mi)
                acc4[mi][ni] = __builtin_amdgcn_mfma_f32_16x16x32_bf16(a[mi], bc4[ni], acc4[mi][ni], 0, 0, 0);
#pragma unroll
        for (int ni = 0; ni < 2; ++ni) bc4[ni] = bn4[ni];
    }

    // stat4 partials
#pragma unroll
    for (int ni = 0; ni < 2; ++ni) {
        float s = 0.f, q = 0.f;
#pragma unroll
        for (int mi = 0; mi < 4; ++mi)
#pragma unroll
            for (int r = 0; r < 4; ++r) {
                int rowg = rowbase + mi * 16 + lg * 4 + r;
                float v = (rowg < NN) ? acc4[mi][ni][r] : 0.f;
                s += v; q += v * v;
            }
        s += __shfl_xor(s, 16); s += __shfl_xor(s, 32);
        q += __shfl_xor(q, 16); q += __shfl_xor(q, 32);
        if (lg == 0) {
            int ch = (cb02 + ni) * 16 + lm;
            red[ch] = s; red[128 + ch] = q;
        }
    }
    __syncthreads();                     // x3 reads done + red ready

    // scratch writes into buf (pitch 272, 17408 <= 33280) + stats atomics
#pragma unroll
    for (int mi = 0; mi < 4; ++mi)
#pragma unroll
        for (int ni = 0; ni < 2; ++ni)
#pragma unroll
            for (int r = 0; r < 4; ++r) {
                int rloc = mi * 16 + lg * 4 + r;
                int col = (cb02 + ni) * 16 + lm;
                *(unsigned short*)(buf + rloc * 272 + col * 2) = f2b(acc4[mi][ni][r]);
            }
    if (tid < 128) {
        int slice = blockIdx.x & (NSLICE - 1);
        atomicAdd(statsOut + (size_t)slice * 256 + tid,       red[tid]);
        atomicAdd(statsOut + (size_t)slice * 256 + 128 + tid, red[128 + tid]);
    }
    __syncthreads();                     // scratch ready

    // coalesced y4 store
    {
        int rloc = tid >> 2;
        int u0 = (tid & 3) * 4;
        unsigned short* Yrow = Y + (size_t)(rowbase + rloc) * 128 + u0 * 8;
#pragma unroll
        for (int u = 0; u < 4; ++u)
            *(ushort8v*)(Yrow + u * 8) = *(const ushort8v*)(buf + rloc * 272 + (u0 + u) * 16);
    }
}

// ---------------------------------------------------------------------------
// K5: x5 = relu( BN4(y4) + relu(BN2(y2)) ); logits = x5 @ w_out.T + b_out.
// 938 blocks x 128 rows; wT XOR-swizzled; 8 blocks/CU (36 VGPR << 64 cap).
// ---------------------------------------------------------------------------
__global__ __launch_bounds__(256, 8) void k5_kernel(
    const unsigned short* __restrict__ y2, const unsigned short* __restrict__ y4,
    const float* __restrict__ stat2, const float* __restrict__ g2, const float* __restrict__ b2,
    const float* __restrict__ stat4, const float* __restrict__ g4, const float* __restrict__ b4,
    const float* __restrict__ w_out, const float* __restrict__ b_out,
    float* __restrict__ out)
{
    __shared__ float wT[128 * 8];
    __shared__ float sc2[128], bi2[128], sc4[128], bi4[128], bo[8];
    const int tid = threadIdx.x;

    if (tid < 128) {
        float s2 = 0.f, q2 = 0.f, s4 = 0.f, q4 = 0.f;
#pragma unroll 8
        for (int j = 0; j < NSLICE; ++j) {
            s2 += stat2[j * 256 + tid];       q2 += stat2[j * 256 + 128 + tid];
            s4 += stat4[j * 256 + tid];       q4 += stat4[j * 256 + 128 + tid];
        }
        float m2 = s2 * (1.0f / NN);
        float v2 = q2 * (1.0f / NN) - m2 * m2;
        float t2 = g2[tid] * rsqrtf(v2 + EPSV);
        sc2[tid] = t2; bi2[tid] = b2[tid] - m2 * t2;
        float m4 = s4 * (1.0f / NN);
        float v4 = q4 * (1.0f / NN) - m4 * m4;
        float t4 = g4[tid] * rsqrtf(v4 + EPSV);
        sc4[tid] = t4; bi4[tid] = b4[tid] - m4 * t4;
    }
    for (int i = tid; i < 1024; i += 256) {
        float val = w_out[(i & 7) * 128 + (i >> 3)];
        int swz = (((i >> 2) ^ ((i >> 7) & 7)) << 2) | (i & 3);
        wT[swz] = val;
    }
    if (tid < 8) bo[tid] = b_out[tid];
    __syncthreads();

    const int l = tid & 63, wv = tid >> 6;
    const int sub = l & 7, rl = l >> 3;

#pragma unroll
    for (int gi = 0; gi < 4; ++gi) {
        int row = blockIdx.x * 128 + gi * 32 + wv * 8 + rl;
        if (row >= NN) continue;

        const ushort8v* p2 = (const ushort8v*)(y2 + (size_t)row * 128 + sub * 16);
        const ushort8v* p4 = (const ushort8v*)(y4 + (size_t)row * 128 + sub * 16);

        float p[8];
#pragma unroll
        for (int o = 0; o < 8; ++o) p[o] = 0.f;

#pragma unroll
        for (int jj = 0; jj < 2; ++jj) {
            ushort8v a2 = p2[jj];
            ushort8v a4 = p4[jj];
#pragma unroll
            for (int e = 0; e < 8; ++e) {
                int c = sub * 16 + jj * 8 + e;
                float i2 = fmaxf(b2f(a2[e]) * sc2[c] + bi2[c], 0.f);
                float x4 = b2f(a4[e]) * sc4[c] + bi4[c];
                float x5 = fmaxf(x4 + i2, 0.f);
                f32x4 wa = *(const f32x4*)(wT + (((c * 2)     ^ sub) << 2));
                f32x4 wb = *(const f32x4*)(wT + (((c * 2 + 1) ^ sub) << 2));
                p[0] += x5 * wa[0]; p[1] += x5 * wa[1]; p[2] += x5 * wa[2]; p[3] += x5 * wa[3];
                p[4] += x5 * wb[0]; p[5] += x5 * wb[1]; p[6] += x5 * wb[2]; p[7] += x5 * wb[3];
            }
        }
#pragma unroll
        for (int o = 0; o < 8; ++o) {
            p[o] += __shfl_xor(p[o], 1);
            p[o] += __shfl_xor(p[o], 2);
            p[o] += __shfl_xor(p[o], 4);
        }
        out[(size_t)row * 8 + sub] = p[sub] + bo[sub];
    }
}

// ---------------------------------------------------------------------------
extern "C" void kernel_launch(void* const* d_in, const int* in_sizes, int n_in,
                              void* d_out, int out_size, void* d_ws, size_t ws_size,
                              hipStream_t stream)
{
    const float* feat  = (const float*)d_in[0];
    // d_in[1] coord, d_in[2] knn_idx, d_in[3] offset: dead code in reference
    const float* w1    = (const float*)d_in[4];
    const float* g1    = (const float*)d_in[5];
    const float* b1    = (const float*)d_in[6];
    const float* w2    = (const float*)d_in[7];
    const float* g2    = (const float*)d_in[8];
    const float* b2    = (const float*)d_in[9];
    const float* w3    = (const float*)d_in[10];
    const float* g3    = (const float*)d_in[11];
    const float* b3    = (const float*)d_in[12];
    const float* w4    = (const float*)d_in[13];
    const float* g4    = (const float*)d_in[14];
    const float* b4    = (const float*)d_in[15];
    const float* w_out = (const float*)d_in[16];
    const float* b_out = (const float*)d_in[17];

    char* ws = (char*)d_ws;
    const size_t sz128 = (size_t)NP * 128 * 2;   // bf16 N x 128
    unsigned short* y2 = (unsigned short*)(ws);
    unsigned short* y4 = (unsigned short*)(ws + sz128);
    float* stats       = (float*)(ws + 2 * sz128);
    // mom [118][32] @0 (pad to 3840), stat2 [16][2][128] @3840,
    // stat3 [16][2][256] @7936, stat4 [16][2][128] @16128
    float* mom   = stats;
    float* stat2 = stats + 3840;
    float* stat3 = stats + 7936;
    float* stat4 = stats + 16128;
    unsigned short* wb = (unsigned short*)(stats + 20224);  // 81920 bf16 frag weights

    prep_kernel<<<dim3(320 + NMOMB), 256, 0, stream>>>(w2, w3, w4, wb, feat,
                                                       stat2 /*zero region*/, mom);
    gemm1_kernel<<<dim3(1876), 256, 0, stream>>>(feat, w1, g1, b1, mom, wb, y2, stat2);
    gemm2s_kernel<<<dim3(1876), 256, 0, stream>>>(y2, stat2, g2, b2, wb + 16384, stat3);
    gemm34_kernel<<<dim3(1876), 256, 0, stream>>>(y2, stat2, g2, b2, stat3, g3, b3,
                                                  wb + 16384, wb + 49152, y4, stat4);
    k5_kernel<<<dim3(938), 256, 0, stream>>>(y2, y4, stat2, g2, b2, stat4, g4, b4,
                                             w_out, b_out, (float*)d_out);
}